// Round 10
// baseline (136.158 us; speedup 1.0000x reference)
//
#include <hip/hip_runtime.h>
#include <stdint.h>

// ModulatedConv2D: B=8, IC=OC=512, K=3, H=W=32
// 3 dispatches: style (sm, sm2, zero dacc), prep (Wtf fragment repack +
// demod atomicAdd into dacc + xsp fragment repack), conv (implicit GEMM,
// 32x32x16 f16 MFMA, BARRIER-FREE K-loop: wave-private double-buffered X
// staged via global_load_lds; explicit counted s_waitcnt vmcnt(N) keeps the
// prefetch in flight across iterations — never vmcnt(0), no __syncthreads).

#define B_   8
#define IC_  512
#define OC_  512

static constexpr float RC_DENSE = 0.04419417382415922f;   // 1/sqrt(512)
static constexpr float RC_CONV  = 0.014731391274719739f;  // 1/sqrt(4608)

typedef _Float16 half8    __attribute__((ext_vector_type(8)));
typedef float    floatx16 __attribute__((ext_vector_type(16)));

// async global->LDS, 16B per lane; LDS dest = wave-uniform base + lane*16
__device__ __forceinline__ void g2l(const void* g, void* l) {
  __builtin_amdgcn_global_load_lds(
      (const __attribute__((address_space(1))) void*)g,
      (__attribute__((address_space(3))) void*)l, 16, 0, 0);
}

// ---- sm = (w@(RC_DENSE*dw) + db + 1)*RC_CONV ; sm2 = sm^2 ; dacc = 0 ----
__global__ __launch_bounds__(256) void style_kernel(
    const float* __restrict__ wv, const float* __restrict__ dw,
    const float* __restrict__ db, float* __restrict__ sm,
    float* __restrict__ sm2, float* __restrict__ dacc) {
  const int b = blockIdx.y;
  const int i = blockIdx.x * 64 + (threadIdx.x & 63);
  const int jg = threadIdx.x >> 6;
  __shared__ float red[4][64];
  float p = 0.f;
  for (int j = jg * 128; j < jg * 128 + 128; ++j)
    p += wv[b * IC_ + j] * dw[(size_t)j * IC_ + i];
  red[jg][threadIdx.x & 63] = p;
  __syncthreads();
  if (threadIdx.x < 64) {
    float s = red[0][threadIdx.x] + red[1][threadIdx.x] +
              red[2][threadIdx.x] + red[3][threadIdx.x];
    s = s * RC_DENSE + db[i] + 1.0f;
    float v = s * RC_CONV;
    sm[b * IC_ + i] = v;
    sm2[b * IC_ + i] = v * v;
    dacc[b * IC_ + i] = 0.f;   // prep (later in stream) accumulates into this
  }
}

// ---------------- prep: 512 blocks (2/CU) ----------------
// bid<256 (wts role): 32oc x 32ic half-tile; Wtf[by][icb][ktq 36][oc64][8] f16
//   + dacc[b][oc] += sum_icl sm2 * sum_t cw^2 (atomicAdd, dacc pre-zeroed)
// bid>=256 (xsp role): per (b,h) row; xsp[b][icb][r34][kk2][kq2][C34][8] f16
__global__ __launch_bounds__(256) void prep_kernel(
    const float* __restrict__ cw, const float* __restrict__ x,
    const float* __restrict__ sm, const float* __restrict__ sm2,
    _Float16* __restrict__ Wtf, float* __restrict__ dacc,
    _Float16* __restrict__ xsp) {
  __shared__ __align__(16) char smem[33280];
  const int bid = blockIdx.x;
  const int tid = threadIdx.x;
  if (bid < 256) {
    // ---------------- wts + dacc role ----------------
    _Float16* LA = (_Float16*)smem;                // 18432 B
    float* redall = (float*)(smem + 18432);        // 8192 B (8b x 8g x 32oc)
    const int by2 = bid >> 4, icb = bid & 15;
    const int by = by2 >> 1, h2 = by2 & 1;
    const int oc0 = by * 64 + h2 * 32, ic0 = icb * 32;
    const int ocl = tid & 31, g = tid >> 5;        // g 0..7
    float sq4[4] = {};
    for (int m = 0; m < 36; ++m) {
      int r = m * 8 + g;                 // r = t*32+icl; t=m>>2, icl=8*(m&3)+g
      int t = r >> 5, icl = r & 31;
      float v = cw[(size_t)(t * IC_ + ic0 + icl) * OC_ + oc0 + ocl];  // 128B seg
      sq4[m & 3] += v * v;
      LA[m * 256 + ocl * 8 + g] = (_Float16)v;     // ktq == m, j == g
    }
    for (int b = 0; b < 8; ++b) {
      float p = 0.f;
      for (int s = 0; s < 4; ++s)
        p += sm2[b * IC_ + ic0 + g + 8 * s] * sq4[s];
      redall[(b * 8 + g) * 32 + ocl] = p;
    }
    __syncthreads();
    // Wtf: 1152 b128 chunks
    _Float16* dst = Wtf + (size_t)(by * 16 + icb) * 18432;
    for (int it = 0; it < 5; ++it) {
      int c = it * 256 + tid;
      if (c < 1152) {
        int m = c >> 5, o2 = c & 31;
        *(half8*)(dst + (size_t)(m * 64 + h2 * 32 + o2) * 8) =
            *(const half8*)&LA[m * 256 + o2 * 8];
      }
    }
    // dacc: reduce over g, one atomicAdd per (b, oc)
    const int bb = tid >> 5, o3 = tid & 31;
    float s = 0.f;
    for (int g2 = 0; g2 < 8; ++g2) s += redall[(bb * 8 + g2) * 32 + o3];
    atomicAdd(&dacc[bb * OC_ + oc0 + o3], s);
  } else {
    // ---------------- xsp role ----------------
    _Float16* Xt = (_Float16*)smem;                // 32*520*2 = 33280 B
    const int rb = bid - 256;
    const int b = rb >> 5, h = rb & 31;
    for (int k = 0; k < 16; ++k) {
      int idx = k * 256 + tid;           // 512 ic * 8 w-quads
      int ic = idx >> 3, wc = (idx & 7) * 4;
      float4 v = *(const float4*)&x[((size_t)(b * IC_ + ic) * 32 + h) * 32 + wc];
      float s = sm[b * IC_ + ic];
      Xt[(wc + 0) * 520 + ic] = (_Float16)(v.x * s);
      Xt[(wc + 1) * 520 + ic] = (_Float16)(v.y * s);
      Xt[(wc + 2) * 520 + ic] = (_Float16)(v.z * s);
      Xt[(wc + 3) * 520 + ic] = (_Float16)(v.w * s);
    }
    __syncthreads();
    _Float16* xb = xsp + (size_t)b * 16 * 36992;
    const int r = h + 1;
    half8 z = {};
    for (int it = 0; it < 9; ++it) {     // 16 icb * 4 kkq * 34 C = 2176 chunks
      int c = it * 256 + tid;
      if (c < 2176) {
        int icb = c / 136, rem = c - 136 * icb, kkq = rem / 34, C = rem - 34 * kkq;
        half8 val = z;
        if (C != 0 && C != 33)
          val = *(const half8*)&Xt[(C - 1) * 520 + icb * 32 + kkq * 8];
        *(half8*)&xb[(size_t)icb * 36992 + (size_t)r * 1088 + kkq * 272 + C * 8] = val;
      }
    }
    if (h == 0 || h == 31) {             // zero top/bottom padded rows
      const int rz = (h == 0) ? 0 : 33;
      for (int it = 0; it < 9; ++it) {
        int c = it * 256 + tid;
        if (c < 2176) {
          int icb = c / 136, rem = c - 136 * icb, kkq = rem / 34, C = rem - 34 * kkq;
          *(half8*)&xb[(size_t)icb * 36992 + (size_t)rz * 1088 + kkq * 272 + C * 8] = z;
        }
      }
    }
  }
}

// ---- conv: BARRIER-FREE. Wave = 32oc x 64px (2 out rows), private X buffer.
// Block = 2 waves sharing og. Grid (og 16, rq 8, b 8) = 1024 blocks = 4/CU;
// XCD = og%8 -> each XCD's A slice (590 KB) L2-resident.
// Per wave/icb segment: 18 A b128 (global->VGPR) + 9 g2l (X next) = 27 vmem,
// then s_waitcnt vmcnt(27): drains everything OLDER (i.e. X(cur) staging)
// while the 27 new ops stay in flight. asm memory clobbers pin segment
// boundaries so the counts are order-robust. Last iter: vmcnt(18).
__global__ __launch_bounds__(128, 2) void conv_kernel(
    const _Float16* __restrict__ Wtf,   // [8 by][16 icb][36 ktq][64 oc][8]
    const _Float16* __restrict__ xsp,   // [8 b][16 icb][34 r][2 kk][2 kq][34 C][8]
    const float* __restrict__ dacc,     // [8][512] demod sum-of-squares
    float* __restrict__ out) {          // [8][512][32][32]
  const int og = blockIdx.x;            // oc-group of 32: oc0 = og*32
  const int rq = blockIdx.y, b = blockIdx.z;
  const int w = threadIdx.x >> 6, lane = threadIdx.x & 63;
  const int rp = rq * 2 + w;            // row-pair: output rows rp*2, rp*2+1
  const int n = lane & 31, kq = lane >> 5;
  const int R = rp * 2;                 // staged padded rows R..R+3

  // wave-private double buffers: 576 chunks (544 used + 32 slack) x 16 B
  __shared__ __align__(16) _Float16 Xw[2][2][4608];

  const _Float16* gX = xsp + (size_t)b * 16 * 36992 + (size_t)R * 1088;
  const _Float16* gA = Wtf + (size_t)((og >> 1) * 16) * 18432
                       + kq * 512 + ((og & 1) * 32 + n) * 8;

  // prologue: stage X(0) into private buf 0 (9 wave-wide g2l; 32-chunk slack
  // absorbs the over-stage, content of chunks >=544 unused)
  for (int i = 0; i < 9; ++i)
    g2l(gX + (size_t)(i * 64 + lane) * 8, &Xw[w][0][(i * 64 + lane) * 8]);
  asm volatile("" ::: "memory");        // pin: prologue g2l precede loop vmem

  floatx16 acc[2] = {};
  for (int icb = 0; icb < 16; ++icb) {
    const int cur = icb & 1;
    // A for current icb (global->VGPR)
    const _Float16* gAi = gA + (size_t)icb * 18432;
    half8 a[9][2];
#pragma unroll
    for (int t = 0; t < 9; ++t)
#pragma unroll
      for (int kk = 0; kk < 2; ++kk)
        a[t][kk] = *(const half8*)(gAi + (t * 2 + kk) * 1024);
    // prefetch X(icb+1) into the other private buffer — stays in flight
    if (icb < 15) {
      const _Float16* gX1 = gX + (size_t)(icb + 1) * 36992;
#pragma unroll
      for (int i = 0; i < 9; ++i)
        g2l(gX1 + (size_t)(i * 64 + lane) * 8,
            &Xw[w][cur ^ 1][(i * 64 + lane) * 8]);
      // 27 vmem issued this segment; drain everything older (= X(cur) g2l)
      asm volatile("s_waitcnt vmcnt(27)" ::: "memory");
    } else {
      // 18 vmem issued this segment; drain everything older (= X(15) g2l)
      asm volatile("s_waitcnt vmcnt(18)" ::: "memory");
    }
    // compute on X(cur): rows s=0..3, col n+kw, k-half kk
    const _Float16* Xp = &Xw[w][cur][0] + kq * 272 + n * 8;
#pragma unroll
    for (int s = 0; s < 4; ++s) {
#pragma unroll
      for (int kw = 0; kw < 3; ++kw) {
#pragma unroll
        for (int kk = 0; kk < 2; ++kk) {
          half8 xv = *(const half8*)(Xp + s * 1088 + kk * 544 + kw * 8);
#pragma unroll
          for (int kh = 0; kh < 3; ++kh) {
            int j = s - kh;
            if (j >= 0 && j < 2)
              acc[j] = __builtin_amdgcn_mfma_f32_32x32x16_f16(
                  a[kh * 3 + kw][kk], xv, acc[j], 0, 0, 0);
          }
        }
      }
    }
  }

  // epilogue: dv = rsqrt(dacc+1e-8); plain stores.
  // D col(px)=n, row(oc)=(rg&3)+8*(rg>>2)+4*kq; out rows R, R+1
  const int oc0 = og * 32;
#pragma unroll
  for (int rg = 0; rg < 16; ++rg) {
    const int row = (rg & 3) + 8 * (rg >> 2) + 4 * kq;
    const float dv = rsqrtf(dacc[b * OC_ + oc0 + row] + 1e-8f);
    float* op = out + ((size_t)b * OC_ + oc0 + row) * 1024 + R * 32 + n;
    op[0]  = acc[0][rg] * dv;
    op[32] = acc[1][rg] * dv;
  }
}

extern "C" void kernel_launch(void* const* d_in, const int* in_sizes, int n_in,
                              void* d_out, int out_size, void* d_ws, size_t ws_size,
                              hipStream_t stream) {
  const float* x       = (const float*)d_in[0];
  const float* w       = (const float*)d_in[1];
  const float* conv_w  = (const float*)d_in[2];
  const float* dense_w = (const float*)d_in[3];
  const float* dense_b = (const float*)d_in[4];
  float* out = (float*)d_out;

  char* ws = (char*)d_ws;
  float*    sm   = (float*)ws;                         // 16 KB
  float*    sm2  = (float*)(ws + (16 << 10));          // 16 KB
  float*    dacc = (float*)(ws + (32 << 10));          // 16 KB
  _Float16* Wtf  = (_Float16*)(ws + (48 << 10));                 // 4,718,592 B
  _Float16* xsp  = (_Float16*)(ws + (48 << 10) + 4718592);       // 9,469,952 B
  // note: conv's slack over-stage reads <=512 B past xsp end; ws has headroom.

  style_kernel<<<dim3(8, B_), 256, 0, stream>>>(w, dense_w, dense_b, sm, sm2, dacc);
  prep_kernel<<<512, 256, 0, stream>>>(conv_w, x, sm, sm2, Wtf, dacc, xsp);
  conv_kernel<<<dim3(16, 8, B_), 128, 0, stream>>>(Wtf, xsp, dacc, out);
}